// Round 3
// baseline (353.752 us; speedup 1.0000x reference)
//
#include <hip/hip_runtime.h>

// MixSelfAttention (B=2, L=1024, H=8, E=64), float32 in/out.
//
//   K0: transpose Q,K -> Qc/Kc[bh][eg(16)][t(1024)][4e]  (coalesced writes)
//   K1: circular cross-correlation; Q rolling window from LDS (swizzled),
//       K via wave-uniform loads from Kc (scalar-promotable, no LDS);
//       amp2part[bh][eg][tau] = sum_{e in eg} ac^2
//   K3: top-35 per (bh) for both branches, jax tie-break (smallest index)
//   K4: 70 sparse scores per row m + softmax -> P[bh][m][72]  (4 thr/row)
//   KA: gather Wg[bh][m][72] = W[m][col_j]  (coalesced writes, row-local reads)
//   KB: WV[bh][j][d] = sum_m Wg[bh][m][j] * v[b,m,h,d]   (grid 18x16)
//   K6: out[b,l,h,d] = sum_j P[l,j]*WV[j,d] + WV[70,d]
//
// ws (bytes): amp2part@0 1M | St@1M | Stf | P 4.5M | WV 288K | Kc 4M | Qc 4M | Wg 4.5M

#define NTOP 35
#define NJ 70

static __device__ __forceinline__ void fma4(float4& a, float4 q, float4 k) {
  a.x = fmaf(q.x,k.x,a.x); a.y = fmaf(q.y,k.y,a.y);
  a.z = fmaf(q.z,k.z,a.z); a.w = fmaf(q.w,k.w,a.w);
}

// ---------------- K0: [b][t][h][e] -> [bh][eg][t][4] for Q and K ----------------
__global__ __launch_bounds__(256) void k0_trans(
    const float* __restrict__ q, const float* __restrict__ k,
    float* __restrict__ Qc, float* __restrict__ Kc) {
  int gid = blockIdx.x;                 // 256 = 16 bh x 16 tchunk
  int bh = gid >> 4;  int t0 = (gid & 15) << 6;
  int b = bh >> 3, h = bh & 7;
  int tid = threadIdx.x;
  int ti = tid & 63;  int eg4 = tid >> 6;   // covers egs [4*eg4, 4*eg4+4)
  int t = t0 + ti;
  size_t base = (((size_t)(b*1024 + t)*8 + h) << 6) + (eg4 << 4);
  const float4* qp = reinterpret_cast<const float4*>(q + base);
  const float4* kp = reinterpret_cast<const float4*>(k + base);
  float4* Qc4 = reinterpret_cast<float4*>(Qc);
  float4* Kc4 = reinterpret_cast<float4*>(Kc);
  #pragma unroll
  for (int kk = 0; kk < 4; ++kk) {
    size_t idx = (size_t)(bh*16 + (eg4*4 + kk))*1024 + t;
    Qc4[idx] = qp[kk];
    Kc4[idx] = kp[kk];
  }
}

// ---------------- K1: correlation; Q rolling from LDS, K uniform loads ----------------
__global__ __launch_bounds__(256) void k1_corr(
    const float* __restrict__ Qc, const float* __restrict__ Kc,
    float* __restrict__ amp2part) {
  int gid = blockIdx.x;                 // 256 = 16 bh x 16 eg
  int bh = gid & 15;  int eg = gid >> 4;
  __shared__ float4 Qs[1024 + 128];     // pad-swizzled: phys = r + (r>>3)
  int tid = threadIdx.x;
  const float4* Qg = reinterpret_cast<const float4*>(Qc) + (size_t)(bh*16+eg)*1024;
  const float4* Kg = reinterpret_cast<const float4*>(Kc) + (size_t)(bh*16+eg)*1024;
  for (int r = tid; r < 1024; r += 256) Qs[r + (r >> 3)] = Qg[r];
  __syncthreads();
  int tb = tid << 2;                    // 4 consecutive tau per thread
  float4 a0 = make_float4(0,0,0,0), a1 = a0, a2 = a0, a3 = a0;
  float4 q0 = Qs[tb + (tb>>3)];
  int r1 = tb+1, r2 = tb+2, r3 = tb+3;
  float4 q1 = Qs[r1 + (r1>>3)], q2 = Qs[r2 + (r2>>3)], q3 = Qs[r3 + (r3>>3)];
  #pragma unroll 4
  for (int t = 0; t < 1024; ++t) {
    float4 kv = Kg[t];                  // wave-uniform -> scalar load
    fma4(a0, q0, kv); fma4(a1, q1, kv); fma4(a2, q2, kv); fma4(a3, q3, kv);
    q0 = q1; q1 = q2; q2 = q3;
    int rn = (t + tb + 4) & 1023;
    q3 = Qs[rn + (rn >> 3)];
  }
  float4 r;
  r.x = a0.x*a0.x + a0.y*a0.y + a0.z*a0.z + a0.w*a0.w;
  r.y = a1.x*a1.x + a1.y*a1.y + a1.z*a1.z + a1.w*a1.w;
  r.z = a2.x*a2.x + a2.y*a2.y + a2.z*a2.z + a2.w*a2.w;
  r.w = a3.x*a3.x + a3.y*a3.y + a3.z*a3.z + a3.w*a3.w;
  reinterpret_cast<float4*>(amp2part + (size_t)(bh*16+eg)*1024)[tid] = r;
}

// ---------------- K3: top-35 (blocks 0..15: t-branch, 16..31: tf) ----------------
__global__ __launch_bounds__(256) void k3_topk(
    const float* __restrict__ amp2part, const float* __restrict__ tfq,
    int* __restrict__ St, int* __restrict__ Stf) {
  int bid = blockIdx.x;
  bool isT = bid < 16;
  int bh = isT ? bid : bid - 16;
  __shared__ float vals[1024];
  __shared__ long long wred[4];
  int tid = threadIdx.x;
  if (isT) {
    for (int l = tid; l < 1024; l += 256) {
      float s = 0.f;
      #pragma unroll
      for (int eg = 0; eg < 16; ++eg)
        s += amp2part[((size_t)bh*16 + eg)*1024 + l];
      vals[l] = s;
    }
  } else {
    int b = bh >> 3, h = bh & 7;
    for (int l = tid; l < 1024; l += 256) {
      const float4* p = reinterpret_cast<const float4*>(
          tfq + (((size_t)(b*1024 + l)*8 + h) << 6));
      float s = 0.f;
      #pragma unroll
      for (int i = 0; i < 16; ++i) {
        float4 v = p[i];
        s += v.x*v.x + v.y*v.y + v.z*v.z + v.w*v.w;
      }
      vals[l] = s;
    }
  }
  __syncthreads();
  int* out = isT ? (St + bh*40) : (Stf + bh*40);
  for (int it = 0; it < NTOP; ++it) {
    long long best = -0x7FFFFFFFFFFFFFFFLL - 1;
    for (int l = tid; l < 1024; l += 256) {
      long long key = ((long long)(int)__float_as_uint(vals[l]) << 32)
                      | (unsigned int)(1023 - l);
      if (key > best) best = key;
    }
    for (int off = 32; off; off >>= 1) {
      long long o = __shfl_down(best, off);
      if (o > best) best = o;
    }
    if ((tid & 63) == 0) wred[tid >> 6] = best;
    __syncthreads();
    if (tid == 0) {
      long long bb = wred[0];
      for (int w = 1; w < 4; ++w) if (wred[w] > bb) bb = wred[w];
      int idx = 1023 - (int)(bb & 0xFFFFFFFFLL);
      out[it] = idx;
      vals[idx] = -1.0f;
    }
    __syncthreads();
  }
}

// ---------------- K4: sparse scores + softmax -> P[bh][m][72], 4 thr/row ----------------
__global__ __launch_bounds__(256) void k4_scores(
    const float* __restrict__ q, const float* __restrict__ k,
    const float* __restrict__ tfq,
    const int* __restrict__ St, const int* __restrict__ Stf,
    float* __restrict__ P) {
  int gid = blockIdx.x;                 // 256 = 16 bh x 16 mchunk(64)
  int bh = gid >> 4;  int m0 = (gid & 15) << 6;
  int b = bh >> 3, h = bh & 7;
  __shared__ float qs[NTOP*64];
  __shared__ float ts[NTOP*64];
  __shared__ float sc[64*73];           // stride 73: conflict-free
  __shared__ float invs[64];
  int tid = threadIdx.x;
  for (int i = tid; i < NTOP*64; i += 256) {
    int j = i >> 6, e = i & 63;
    int rq = St[bh*40 + j];
    int rt = Stf[bh*40 + j];
    qs[i] = q  [(((size_t)(b*1024 + rq)*8 + h) << 6) + e];
    ts[i] = tfq[(((size_t)(b*1024 + rt)*8 + h) << 6) + e];
  }
  __syncthreads();
  int mi = tid & 63, g = tid >> 6;
  int m = m0 + mi;
  float4 kr[16];
  {
    const float4* p = reinterpret_cast<const float4*>(
        k + (((size_t)(b*1024 + m)*8 + h) << 6));
    #pragma unroll
    for (int i = 0; i < 16; ++i) kr[i] = p[i];
  }
  const float4* qs4 = reinterpret_cast<const float4*>(qs);
  for (int j = g; j < NTOP; j += 4) {
    float s = 0.f;
    #pragma unroll
    for (int e4 = 0; e4 < 16; ++e4) {
      float4 qv = qs4[j*16 + e4];
      s += qv.x*kr[e4].x + qv.y*kr[e4].y + qv.z*kr[e4].z + qv.w*kr[e4].w;
    }
    sc[mi*73 + j] = s * 0.125f;
  }
  {
    const float4* p = reinterpret_cast<const float4*>(
        tfq + (((size_t)(b*1024 + m)*8 + h) << 6));
    #pragma unroll
    for (int i = 0; i < 16; ++i) kr[i] = p[i];
  }
  const float4* ts4 = reinterpret_cast<const float4*>(ts);
  for (int j = g; j < NTOP; j += 4) {
    float s = 0.f;
    #pragma unroll
    for (int e4 = 0; e4 < 16; ++e4) {
      float4 qv = ts4[j*16 + e4];
      s += qv.x*kr[e4].x + qv.y*kr[e4].y + qv.z*kr[e4].z + qv.w*kr[e4].w;
    }
    sc[mi*73 + NTOP + j] = s * 0.125f;
  }
  __syncthreads();
  if (tid < 64) {                       // wave 0: softmax factors per row
    float mx = -1e30f;
    for (int j = 0; j < NJ; ++j) mx = fmaxf(mx, sc[tid*73 + j]);
    float sum = 0.f;
    for (int j = 0; j < NJ; ++j) {
      float e = __expf(sc[tid*73 + j] - mx);
      sc[tid*73 + j] = e; sum += e;
    }
    invs[tid] = 1.0f / sum;
  }
  __syncthreads();
  float* Pb = P + ((size_t)bh*1024 + m0)*72;
  for (int i = tid; i < 64*72; i += 256) {
    int mm = i / 72, j = i - mm*72;
    Pb[i] = (j < NJ) ? sc[mm*73 + j] * invs[mm] : 0.f;
  }
}

// ---------------- KA: gather Wg[bh][m][72] ----------------
__global__ __launch_bounds__(256) void ka_gather(
    const float* __restrict__ w, const float* __restrict__ bias,
    const int* __restrict__ St, const int* __restrict__ Stf,
    float* __restrict__ Wg) {
  int gid = blockIdx.x;                 // 256 = 16 bh x 16 mchunk(64)
  int bh = gid >> 4;  int m0 = (gid & 15) << 6;
  __shared__ int cols[72];
  int tid = threadIdx.x;
  if (tid < NTOP)      cols[tid] = St[bh*40 + tid];
  else if (tid < NJ)   cols[tid] = 1024 + Stf[bh*40 + tid - NTOP];
  else if (tid < 72)   cols[tid] = (tid == NJ) ? -1 : -2;  // bias / zero
  __syncthreads();
  float* dst = Wg + ((size_t)bh*1024 + m0)*72;
  for (int i = tid; i < 64*72; i += 256) {
    int m = m0 + i/72, j = i - (i/72)*72;
    int c = cols[j];
    float v = (c >= 0) ? w[(size_t)m*2048 + c] : ((c == -1) ? bias[m] : 0.f);
    dst[i] = v;
  }
}

// ---------------- KB: WV[bh][j][d] = sum_m Wg[bh][m][j]*v[b,m,h,d] ----------------
__global__ __launch_bounds__(256) void kb_wv(
    const float* __restrict__ Wg, const float* __restrict__ values,
    float* __restrict__ WV) {
  int jq = blockIdx.x;                  // 0..17 -> j0 = 4*jq
  int bh = blockIdx.y;                  // 0..15
  int b = bh >> 3, h = bh & 7;
  int j0 = jq << 2;
  int tid = threadIdx.x;
  int d = tid & 63, mp = tid >> 6;
  float a0=0.f, a1=0.f, a2=0.f, a3=0.f;
  const float* Wgb = Wg + (size_t)bh*1024*72;
  for (int m = mp; m < 1024; m += 4) {
    float vv = values[(((size_t)(b*1024 + m)*8 + h) << 6) + d];
    float4 wv = *reinterpret_cast<const float4*>(Wgb + (size_t)m*72 + j0);
    a0 = fmaf(wv.x, vv, a0); a1 = fmaf(wv.y, vv, a1);
    a2 = fmaf(wv.z, vv, a2); a3 = fmaf(wv.w, vv, a3);
  }
  __shared__ float4 red[256];
  red[tid] = make_float4(a0, a1, a2, a3);
  __syncthreads();
  int jj = tid >> 6, dd = tid & 63;
  float4 r0 = red[dd], r1 = red[64+dd], r2 = red[128+dd], r3 = red[192+dd];
  float s;
  if (jj == 0)      s = r0.x + r1.x + r2.x + r3.x;
  else if (jj == 1) s = r0.y + r1.y + r2.y + r3.y;
  else if (jj == 2) s = r0.z + r1.z + r2.z + r3.z;
  else              s = r0.w + r1.w + r2.w + r3.w;
  WV[((size_t)bh*72 + j0 + jj)*64 + dd] = s;
}

// ---------------- K6: out[b,l,h,d] ----------------
__global__ __launch_bounds__(512) void k6_out(
    const float* __restrict__ P, const float* __restrict__ WV,
    float* __restrict__ out) {
  int l = blockIdx.x, b = blockIdx.y;
  int tid = threadIdx.x;
  int h = tid >> 6, d = tid & 63;
  int bh = b*8 + h;
  const float* Pr = P + ((size_t)bh*1024 + l)*72;
  const float* Wv = WV + (size_t)bh*72*64;
  float acc = Wv[NJ*64 + d];
  for (int j = 0; j < NJ; ++j) acc = fmaf(Pr[j], Wv[j*64 + d], acc);
  out[(((size_t)(b*1024 + l)*8 + h) << 6) + d] = acc;
}

extern "C" void kernel_launch(void* const* d_in, const int* in_sizes, int n_in,
                              void* d_out, int out_size, void* d_ws, size_t ws_size,
                              hipStream_t stream) {
  const float* tfq  = (const float*)d_in[0];
  const float* q    = (const float*)d_in[1];
  const float* k    = (const float*)d_in[2];
  const float* v    = (const float*)d_in[3];
  const float* tw   = (const float*)d_in[5];
  const float* tb   = (const float*)d_in[6];
  float* out = (float*)d_out;

  char* ws = (char*)d_ws;
  float* amp2part = (float*)(ws);                   // 1,048,576
  int*   St       = (int*)  (ws + 1048576);         // 4 KB
  int*   Stf      = (int*)  (ws + 1052672);         // 4 KB
  float* P        = (float*)(ws + 1056768);         // 4,718,592
  float* WV       = (float*)(ws + 5775360);         // 294,912
  float* Kc       = (float*)(ws + 6070272);         // 4,194,304
  float* Qc       = (float*)(ws + 10264576);        // 4,194,304
  float* Wg       = (float*)(ws + 14458880);        // 4,718,592

  k0_trans  <<<256, 256, 0, stream>>>(q, k, Qc, Kc);
  k1_corr   <<<256, 256, 0, stream>>>(Qc, Kc, amp2part);
  k3_topk   <<<32, 256, 0, stream>>>(amp2part, tfq, St, Stf);
  k4_scores <<<256, 256, 0, stream>>>(q, k, tfq, St, Stf, P);
  ka_gather <<<256, 256, 0, stream>>>(tw, tb, St, Stf, Wg);
  kb_wv     <<<dim3(18, 16), 256, 0, stream>>>(Wg, v, WV);
  k6_out    <<<dim3(1024, 2), 512, 0, stream>>>(P, WV, out);
}

// Round 4
// 271.174 us; speedup vs baseline: 1.3045x; 1.3045x over previous
//
#include <hip/hip_runtime.h>

// MixSelfAttention (B=2, L=1024, H=8, E=64), float32 in/out.
//
//   K0: transpose Q,K -> Qc/Kc[bh][eg(16)][t(1024)][4e]  (coalesced writes)
//   K1: circular cross-correlation, grid (16bh x 16eg x 4tc), t-chunk 256;
//       Q plane-major in LDS (conflict-free rolling reads), K chunk in LDS;
//       writes ac partials acp[be][tc][tau][4e]
//   K2: combine 4 t-chunks, square, sum over 4e -> amp2part[be][tau]
//   K3: top-35 per (bh) both branches, jax tie-break (smallest index)
//   KW: tile-transpose W[1024][2048] -> Wt[2048][1024]  (all coalesced)
//   KA2: gather Wg[bh][m][72] from Wt rows via LDS transpose (all coalesced)
//   K4: 70 sparse scores per row m + softmax -> P[bh][m][72]
//   KB: WV[bh][j][d] = sum_m Wg[bh][m][j] * v[b,m,h,d]
//   K6: out[b,l,h,d] = sum_j P[l,j]*WV[j,d] + WV[70,d]
//
// ws (256 MB available; ~42 MB used, no overlaps)

#define NTOP 35
#define NJ 70

static __device__ __forceinline__ void fma4(float4& a, float4 q, float4 k) {
  a.x = fmaf(q.x,k.x,a.x); a.y = fmaf(q.y,k.y,a.y);
  a.z = fmaf(q.z,k.z,a.z); a.w = fmaf(q.w,k.w,a.w);
}

// ---------------- K0: [b][t][h][e] -> [bh][eg][t][4] for Q and K ----------------
__global__ __launch_bounds__(256) void k0_trans(
    const float* __restrict__ q, const float* __restrict__ k,
    float* __restrict__ Qc, float* __restrict__ Kc) {
  int gid = blockIdx.x;                 // 256 = 16 bh x 16 tchunk
  int bh = gid >> 4;  int t0 = (gid & 15) << 6;
  int b = bh >> 3, h = bh & 7;
  int tid = threadIdx.x;
  int ti = tid & 63;  int eg4 = tid >> 6;
  int t = t0 + ti;
  size_t base = (((size_t)(b*1024 + t)*8 + h) << 6) + (eg4 << 4);
  const float4* qp = reinterpret_cast<const float4*>(q + base);
  const float4* kp = reinterpret_cast<const float4*>(k + base);
  float4* Qc4 = reinterpret_cast<float4*>(Qc);
  float4* Kc4 = reinterpret_cast<float4*>(Kc);
  #pragma unroll
  for (int kk = 0; kk < 4; ++kk) {
    size_t idx = (size_t)(bh*16 + (eg4*4 + kk))*1024 + t;
    Qc4[idx] = qp[kk];
    Kc4[idx] = kp[kk];
  }
}

// ---------------- K1: correlation partials over a 256-wide t-chunk ----------------
__global__ __launch_bounds__(256) void k1_corr(
    const float* __restrict__ Qc, const float* __restrict__ Kc,
    float* __restrict__ acp) {
  int gid = blockIdx.x;                 // 1024 = 16 bh | 16 eg | 4 tc
  int bh = gid & 15;  int eg = (gid >> 4) & 15;  int tc = gid >> 8;
  __shared__ float4 QP[1024];           // plane-major: [u=r&3][r>>2]
  __shared__ float4 Ks[256];
  int tid = threadIdx.x;
  const float4* Qg = reinterpret_cast<const float4*>(Qc) + (size_t)(bh*16+eg)*1024;
  const float4* Kg = reinterpret_cast<const float4*>(Kc) + (size_t)(bh*16+eg)*1024;
  int t0 = tc << 8;
  for (int r = tid; r < 1024; r += 256)
    QP[(r & 3)*256 + (r >> 2)] = Qg[r];
  Ks[tid] = Kg[t0 + tid];
  __syncthreads();
  float4 a0 = make_float4(0,0,0,0), a1 = a0, a2 = a0, a3 = a0;
  int i0 = ((t0 >> 2) + tid) & 255;
  float4 q0 = QP[i0], q1 = QP[256 + i0], q2 = QP[512 + i0], q3 = QP[768 + i0];
  int base = (t0 >> 2) + 1 + tid;
  for (int a = 0; a < 64; ++a) {
    int ia = (base + a) & 255;
    int s4 = a << 2;
    float4 kv = Ks[s4];
    fma4(a0,q0,kv); fma4(a1,q1,kv); fma4(a2,q2,kv); fma4(a3,q3,kv);
    q0=q1; q1=q2; q2=q3; q3 = QP[ia];
    kv = Ks[s4+1];
    fma4(a0,q0,kv); fma4(a1,q1,kv); fma4(a2,q2,kv); fma4(a3,q3,kv);
    q0=q1; q1=q2; q2=q3; q3 = QP[256 + ia];
    kv = Ks[s4+2];
    fma4(a0,q0,kv); fma4(a1,q1,kv); fma4(a2,q2,kv); fma4(a3,q3,kv);
    q0=q1; q1=q2; q2=q3; q3 = QP[512 + ia];
    kv = Ks[s4+3];
    fma4(a0,q0,kv); fma4(a1,q1,kv); fma4(a2,q2,kv); fma4(a3,q3,kv);
    q0=q1; q1=q2; q2=q3; q3 = QP[768 + ia];
  }
  // tau = 4*tid + j, chunk tc
  float4* out = reinterpret_cast<float4*>(acp)
              + (((size_t)((bh*16+eg)*4 + tc)) << 10) + (tid << 2);
  out[0]=a0; out[1]=a1; out[2]=a2; out[3]=a3;
}

// ---------------- K2: sum 4 chunks, square, reduce over 4e ----------------
__global__ __launch_bounds__(256) void k2_combine(
    const float* __restrict__ acp, float* __restrict__ amp2part) {
  int be = blockIdx.x;                  // 0..255 = bh*16+eg
  int tid = threadIdx.x;
  const float4* A = reinterpret_cast<const float4*>(acp) + ((size_t)be << 12);
  #pragma unroll
  for (int p = 0; p < 4; ++p) {
    int tau = tid + (p << 8);
    float4 s0 = A[tau], s1 = A[1024 + tau], s2 = A[2048 + tau], s3 = A[3072 + tau];
    float x = s0.x + s1.x + s2.x + s3.x;
    float y = s0.y + s1.y + s2.y + s3.y;
    float z = s0.z + s1.z + s2.z + s3.z;
    float w = s0.w + s1.w + s2.w + s3.w;
    amp2part[(size_t)be*1024 + tau] = x*x + y*y + z*z + w*w;
  }
}

// ---------------- K3: top-35 (blocks 0..15: t-branch, 16..31: tf) ----------------
__global__ __launch_bounds__(256) void k3_topk(
    const float* __restrict__ amp2part, const float* __restrict__ tfq,
    int* __restrict__ St, int* __restrict__ Stf) {
  int bid = blockIdx.x;
  bool isT = bid < 16;
  int bh = isT ? bid : bid - 16;
  __shared__ float vals[1024];
  __shared__ long long wred[4];
  int tid = threadIdx.x;
  if (isT) {
    for (int l = tid; l < 1024; l += 256) {
      float s = 0.f;
      #pragma unroll
      for (int eg = 0; eg < 16; ++eg)
        s += amp2part[((size_t)bh*16 + eg)*1024 + l];
      vals[l] = s;
    }
  } else {
    int b = bh >> 3, h = bh & 7;
    for (int l = tid; l < 1024; l += 256) {
      const float4* p = reinterpret_cast<const float4*>(
          tfq + (((size_t)(b*1024 + l)*8 + h) << 6));
      float s = 0.f;
      #pragma unroll
      for (int i = 0; i < 16; ++i) {
        float4 v = p[i];
        s += v.x*v.x + v.y*v.y + v.z*v.z + v.w*v.w;
      }
      vals[l] = s;
    }
  }
  __syncthreads();
  int* out = isT ? (St + bh*40) : (Stf + bh*40);
  for (int it = 0; it < NTOP; ++it) {
    long long best = -0x7FFFFFFFFFFFFFFFLL - 1;
    for (int l = tid; l < 1024; l += 256) {
      long long key = ((long long)(int)__float_as_uint(vals[l]) << 32)
                      | (unsigned int)(1023 - l);
      if (key > best) best = key;
    }
    for (int off = 32; off; off >>= 1) {
      long long o = __shfl_down(best, off);
      if (o > best) best = o;
    }
    if ((tid & 63) == 0) wred[tid >> 6] = best;
    __syncthreads();
    if (tid == 0) {
      long long bb = wred[0];
      for (int w = 1; w < 4; ++w) if (wred[w] > bb) bb = wred[w];
      int idx = 1023 - (int)(bb & 0xFFFFFFFFLL);
      out[it] = idx;
      vals[idx] = -1.0f;
    }
    __syncthreads();
  }
}

// ---------------- KW: W[1024][2048] -> Wt[2048][1024], 64x64 LDS tiles ----------------
__global__ __launch_bounds__(256) void kw_trans(
    const float* __restrict__ w, float* __restrict__ Wt) {
  __shared__ float tile[64*65];
  int c0 = blockIdx.x << 6;             // 32 tiles
  int r0 = blockIdx.y << 6;             // 16 tiles
  int tid = threadIdx.x;
  #pragma unroll
  for (int s = 0; s < 16; ++s) {
    int idx = tid + (s << 8);
    int r = idx >> 6, c = idx & 63;
    tile[r*65 + c] = w[(size_t)(r0 + r)*2048 + c0 + c];
  }
  __syncthreads();
  #pragma unroll
  for (int s = 0; s < 16; ++s) {
    int idx = tid + (s << 8);
    int c = idx >> 6, r = idx & 63;
    Wt[(size_t)(c0 + c)*1024 + r0 + r] = tile[r*65 + c];
  }
}

// ---------------- KA2: Wg[bh][m][72] from Wt rows via LDS transpose ----------------
__global__ __launch_bounds__(256) void ka2_gather(
    const float* __restrict__ Wt, const float* __restrict__ bias,
    const int* __restrict__ St, const int* __restrict__ Stf,
    float* __restrict__ Wg) {
  int gid = blockIdx.x;                 // 256 = 16 bh x 16 mchunk(64)
  int bh = gid >> 4;  int m0 = (gid & 15) << 6;
  __shared__ int cols[72];
  __shared__ float Wlds[72*65];
  int tid = threadIdx.x;
  if (tid < NTOP)      cols[tid] = St[bh*40 + tid];
  else if (tid < NJ)   cols[tid] = 1024 + Stf[bh*40 + tid - NTOP];
  else if (tid < 72)   cols[tid] = (tid == NJ) ? -1 : -2;
  __syncthreads();
  for (int i = tid; i < 72*64; i += 256) {      // coalesced reads of Wt rows
    int j = i >> 6, mm = i & 63;
    int c = cols[j];
    float v = (c >= 0) ? Wt[(size_t)c*1024 + m0 + mm]
                       : ((c == -1) ? bias[m0 + mm] : 0.f);
    Wlds[j*65 + mm] = v;
  }
  __syncthreads();
  float* dst = Wg + ((size_t)bh*1024 + m0)*72;
  for (int i = tid; i < 64*72; i += 256) {      // coalesced writes of Wg
    int m = i / 72, j = i - m*72;
    dst[i] = Wlds[j*65 + m];
  }
}

// ---------------- K4: sparse scores + softmax -> P[bh][m][72] ----------------
__global__ __launch_bounds__(256) void k4_scores(
    const float* __restrict__ q, const float* __restrict__ k,
    const float* __restrict__ tfq,
    const int* __restrict__ St, const int* __restrict__ Stf,
    float* __restrict__ P) {
  int gid = blockIdx.x;                 // 256 = 16 bh x 16 mchunk(64)
  int bh = gid >> 4;  int m0 = (gid & 15) << 6;
  int b = bh >> 3, h = bh & 7;
  __shared__ float qs[NTOP*64];
  __shared__ float ts[NTOP*64];
  __shared__ float sc[64*73];
  __shared__ float invs[64];
  int tid = threadIdx.x;
  for (int i = tid; i < NTOP*64; i += 256) {
    int j = i >> 6, e = i & 63;
    int rq = St[bh*40 + j];
    int rt = Stf[bh*40 + j];
    qs[i] = q  [(((size_t)(b*1024 + rq)*8 + h) << 6) + e];
    ts[i] = tfq[(((size_t)(b*1024 + rt)*8 + h) << 6) + e];
  }
  __syncthreads();
  int mi = tid & 63, g = tid >> 6;
  int m = m0 + mi;
  float4 kr[16];
  {
    const float4* p = reinterpret_cast<const float4*>(
        k + (((size_t)(b*1024 + m)*8 + h) << 6));
    #pragma unroll
    for (int i = 0; i < 16; ++i) kr[i] = p[i];
  }
  const float4* qs4 = reinterpret_cast<const float4*>(qs);
  for (int j = g; j < NTOP; j += 4) {
    float s = 0.f;
    #pragma unroll
    for (int e4 = 0; e4 < 16; ++e4) {
      float4 qv = qs4[j*16 + e4];
      s += qv.x*kr[e4].x + qv.y*kr[e4].y + qv.z*kr[e4].z + qv.w*kr[e4].w;
    }
    sc[mi*73 + j] = s * 0.125f;
  }
  {
    const float4* p = reinterpret_cast<const float4*>(
        tfq + (((size_t)(b*1024 + m)*8 + h) << 6));
    #pragma unroll
    for (int i = 0; i < 16; ++i) kr[i] = p[i];
  }
  const float4* ts4 = reinterpret_cast<const float4*>(ts);
  for (int j = g; j < NTOP; j += 4) {
    float s = 0.f;
    #pragma unroll
    for (int e4 = 0; e4 < 16; ++e4) {
      float4 qv = ts4[j*16 + e4];
      s += qv.x*kr[e4].x + qv.y*kr[e4].y + qv.z*kr[e4].z + qv.w*kr[e4].w;
    }
    sc[mi*73 + NTOP + j] = s * 0.125f;
  }
  __syncthreads();
  if (tid < 64) {
    float mx = -1e30f;
    for (int j = 0; j < NJ; ++j) mx = fmaxf(mx, sc[tid*73 + j]);
    float sum = 0.f;
    for (int j = 0; j < NJ; ++j) {
      float e = __expf(sc[tid*73 + j] - mx);
      sc[tid*73 + j] = e; sum += e;
    }
    invs[tid] = 1.0f / sum;
  }
  __syncthreads();
  float* Pb = P + ((size_t)bh*1024 + m0)*72;
  for (int i = tid; i < 64*72; i += 256) {
    int mm = i / 72, j = i - mm*72;
    Pb[i] = (j < NJ) ? sc[mm*73 + j] * invs[mm] : 0.f;
  }
}

// ---------------- KB: WV[bh][j][d] = sum_m Wg[bh][m][j]*v[b,m,h,d] ----------------
__global__ __launch_bounds__(256) void kb_wv(
    const float* __restrict__ Wg, const float* __restrict__ values,
    float* __restrict__ WV) {
  int jq = blockIdx.x;                  // 0..17 -> j0 = 4*jq
  int bh = blockIdx.y;                  // 0..15
  int b = bh >> 3, h = bh & 7;
  int j0 = jq << 2;
  int tid = threadIdx.x;
  int d = tid & 63, mp = tid >> 6;
  float a0=0.f, a1=0.f, a2=0.f, a3=0.f;
  const float* Wgb = Wg + (size_t)bh*1024*72;
  for (int m = mp; m < 1024; m += 4) {
    float vv = values[(((size_t)(b*1024 + m)*8 + h) << 6) + d];
    float4 wv = *reinterpret_cast<const float4*>(Wgb + (size_t)m*72 + j0);
    a0 = fmaf(wv.x, vv, a0); a1 = fmaf(wv.y, vv, a1);
    a2 = fmaf(wv.z, vv, a2); a3 = fmaf(wv.w, vv, a3);
  }
  __shared__ float4 red[256];
  red[tid] = make_float4(a0, a1, a2, a3);
  __syncthreads();
  int jj = tid >> 6, dd = tid & 63;
  float4 r0 = red[dd], r1 = red[64+dd], r2 = red[128+dd], r3 = red[192+dd];
  float s;
  if (jj == 0)      s = r0.x + r1.x + r2.x + r3.x;
  else if (jj == 1) s = r0.y + r1.y + r2.y + r3.y;
  else if (jj == 2) s = r0.z + r1.z + r2.z + r3.z;
  else              s = r0.w + r1.w + r2.w + r3.w;
  WV[((size_t)bh*72 + j0 + jj)*64 + dd] = s;
}

// ---------------- K6: out[b,l,h,d] ----------------
__global__ __launch_bounds__(512) void k6_out(
    const float* __restrict__ P, const float* __restrict__ WV,
    float* __restrict__ out) {
  int l = blockIdx.x, b = blockIdx.y;
  int tid = threadIdx.x;
  int h = tid >> 6, d = tid & 63;
  int bh = b*8 + h;
  const float* Pr = P + ((size_t)bh*1024 + l)*72;
  const float* Wv = WV + (size_t)bh*72*64;
  float acc = Wv[NJ*64 + d];
  for (int j = 0; j < NJ; ++j) acc = fmaf(Pr[j], Wv[j*64 + d], acc);
  out[(((size_t)(b*1024 + l)*8 + h) << 6) + d] = acc;
}

extern "C" void kernel_launch(void* const* d_in, const int* in_sizes, int n_in,
                              void* d_out, int out_size, void* d_ws, size_t ws_size,
                              hipStream_t stream) {
  const float* tfq  = (const float*)d_in[0];
  const float* q    = (const float*)d_in[1];
  const float* k    = (const float*)d_in[2];
  const float* v    = (const float*)d_in[3];
  const float* tw   = (const float*)d_in[5];
  const float* tb   = (const float*)d_in[6];
  float* out = (float*)d_out;

  char* ws = (char*)d_ws;
  float* acp      = (float*)(ws);                   // 16,777,216
  float* amp2part = (float*)(ws + 16777216);        // 1,048,576
  int*   St       = (int*)  (ws + 17825792);        // 4 KB
  int*   Stf      = (int*)  (ws + 17829888);        // 4 KB
  float* Qc       = (float*)(ws + 17833984);        // 4,194,304
  float* Kc       = (float*)(ws + 22028288);        // 4,194,304
  float* Wt       = (float*)(ws + 26222592);        // 8,388,608
  float* Wg       = (float*)(ws + 34611200);        // 4,718,592
  float* P        = (float*)(ws + 39329792);        // 4,718,592
  float* WV       = (float*)(ws + 44048384);        // 294,912

  k0_trans  <<<256, 256, 0, stream>>>(q, k, Qc, Kc);
  k1_corr   <<<1024, 256, 0, stream>>>(Qc, Kc, acp);
  k2_combine<<<256, 256, 0, stream>>>(acp, amp2part);
  k3_topk   <<<32, 256, 0, stream>>>(amp2part, tfq, St, Stf);
  kw_trans  <<<dim3(32, 16), 256, 0, stream>>>(tw, Wt);
  ka2_gather<<<256, 256, 0, stream>>>(Wt, tb, St, Stf, Wg);
  k4_scores <<<256, 256, 0, stream>>>(q, k, tfq, St, Stf, P);
  kb_wv     <<<dim3(18, 16), 256, 0, stream>>>(Wg, v, WV);
  k6_out    <<<dim3(1024, 2), 512, 0, stream>>>(P, WV, out);
}

// Round 5
// 225.551 us; speedup vs baseline: 1.5684x; 1.2023x over previous
//
#include <hip/hip_runtime.h>

// MixSelfAttention (B=2, L=1024, H=8, E=64), float32 in/out.
//
//   K0: transpose Q,K -> Qc/Kc[bh][eg(16)][t(1024)][4e]  (coalesced writes)
//   K1: circular cross-correlation, grid (16bh x 16eg x 4tc), t-chunk 256;
//       Q plane-major in LDS (conflict-free rolling reads), K chunk in LDS;
//       writes ac partials acp[be][tc][tau][4e]
//   K2: combine 4 t-chunks, square, sum over 4e -> amp2part[be][tau]
//   K3: top-35 per (bh) both branches, jax tie-break (smallest index)
//   KW: tile-transpose W[1024][2048] -> Wt[2048][1024]  (all coalesced)
//   KA2: gather Wg[bh][m][72] from Wt rows via LDS transpose (all coalesced)
//   K4: 70 sparse scores per row m + softmax -> P[bh][m][72]
//   KB: WVp[mc][bh][j][d] = sum_{m in chunk mc} Wg[bh][m][j]*v[b,m,h,d]
//       grid (18 jq x 16 bh x 4 mc) = 1152 blocks for latency hiding
//   KC: WV = sum_mc WVp
//   K6: out[b,l,h,d] = sum_j P[l,j]*WV[j,d] + WV[70,d]

#define NTOP 35
#define NJ 70

static __device__ __forceinline__ void fma4(float4& a, float4 q, float4 k) {
  a.x = fmaf(q.x,k.x,a.x); a.y = fmaf(q.y,k.y,a.y);
  a.z = fmaf(q.z,k.z,a.z); a.w = fmaf(q.w,k.w,a.w);
}

// ---------------- K0: [b][t][h][e] -> [bh][eg][t][4] for Q and K ----------------
__global__ __launch_bounds__(256) void k0_trans(
    const float* __restrict__ q, const float* __restrict__ k,
    float* __restrict__ Qc, float* __restrict__ Kc) {
  int gid = blockIdx.x;                 // 256 = 16 bh x 16 tchunk
  int bh = gid >> 4;  int t0 = (gid & 15) << 6;
  int b = bh >> 3, h = bh & 7;
  int tid = threadIdx.x;
  int ti = tid & 63;  int eg4 = tid >> 6;
  int t = t0 + ti;
  size_t base = (((size_t)(b*1024 + t)*8 + h) << 6) + (eg4 << 4);
  const float4* qp = reinterpret_cast<const float4*>(q + base);
  const float4* kp = reinterpret_cast<const float4*>(k + base);
  float4* Qc4 = reinterpret_cast<float4*>(Qc);
  float4* Kc4 = reinterpret_cast<float4*>(Kc);
  #pragma unroll
  for (int kk = 0; kk < 4; ++kk) {
    size_t idx = (size_t)(bh*16 + (eg4*4 + kk))*1024 + t;
    Qc4[idx] = qp[kk];
    Kc4[idx] = kp[kk];
  }
}

// ---------------- K1: correlation partials over a 256-wide t-chunk ----------------
__global__ __launch_bounds__(256) void k1_corr(
    const float* __restrict__ Qc, const float* __restrict__ Kc,
    float* __restrict__ acp) {
  int gid = blockIdx.x;                 // 1024 = 16 bh | 16 eg | 4 tc
  int bh = gid & 15;  int eg = (gid >> 4) & 15;  int tc = gid >> 8;
  __shared__ float4 QP[1024];           // plane-major: [u=r&3][r>>2]
  __shared__ float4 Ks[256];
  int tid = threadIdx.x;
  const float4* Qg = reinterpret_cast<const float4*>(Qc) + (size_t)(bh*16+eg)*1024;
  const float4* Kg = reinterpret_cast<const float4*>(Kc) + (size_t)(bh*16+eg)*1024;
  int t0 = tc << 8;
  for (int r = tid; r < 1024; r += 256)
    QP[(r & 3)*256 + (r >> 2)] = Qg[r];
  Ks[tid] = Kg[t0 + tid];
  __syncthreads();
  float4 a0 = make_float4(0,0,0,0), a1 = a0, a2 = a0, a3 = a0;
  int i0 = ((t0 >> 2) + tid) & 255;
  float4 q0 = QP[i0], q1 = QP[256 + i0], q2 = QP[512 + i0], q3 = QP[768 + i0];
  int base = (t0 >> 2) + 1 + tid;
  for (int a = 0; a < 64; ++a) {
    int ia = (base + a) & 255;
    int s4 = a << 2;
    float4 kv = Ks[s4];
    fma4(a0,q0,kv); fma4(a1,q1,kv); fma4(a2,q2,kv); fma4(a3,q3,kv);
    q0=q1; q1=q2; q2=q3; q3 = QP[ia];
    kv = Ks[s4+1];
    fma4(a0,q0,kv); fma4(a1,q1,kv); fma4(a2,q2,kv); fma4(a3,q3,kv);
    q0=q1; q1=q2; q2=q3; q3 = QP[256 + ia];
    kv = Ks[s4+2];
    fma4(a0,q0,kv); fma4(a1,q1,kv); fma4(a2,q2,kv); fma4(a3,q3,kv);
    q0=q1; q1=q2; q2=q3; q3 = QP[512 + ia];
    kv = Ks[s4+3];
    fma4(a0,q0,kv); fma4(a1,q1,kv); fma4(a2,q2,kv); fma4(a3,q3,kv);
    q0=q1; q1=q2; q2=q3; q3 = QP[768 + ia];
  }
  float4* out = reinterpret_cast<float4*>(acp)
              + (((size_t)((bh*16+eg)*4 + tc)) << 10) + (tid << 2);
  out[0]=a0; out[1]=a1; out[2]=a2; out[3]=a3;
}

// ---------------- K2: sum 4 chunks, square, reduce over 4e ----------------
__global__ __launch_bounds__(256) void k2_combine(
    const float* __restrict__ acp, float* __restrict__ amp2part) {
  int be = blockIdx.x;                  // 0..255 = bh*16+eg
  int tid = threadIdx.x;
  const float4* A = reinterpret_cast<const float4*>(acp) + ((size_t)be << 12);
  #pragma unroll
  for (int p = 0; p < 4; ++p) {
    int tau = tid + (p << 8);
    float4 s0 = A[tau], s1 = A[1024 + tau], s2 = A[2048 + tau], s3 = A[3072 + tau];
    float x = s0.x + s1.x + s2.x + s3.x;
    float y = s0.y + s1.y + s2.y + s3.y;
    float z = s0.z + s1.z + s2.z + s3.z;
    float w = s0.w + s1.w + s2.w + s3.w;
    amp2part[(size_t)be*1024 + tau] = x*x + y*y + z*z + w*w;
  }
}

// ---------------- K3: top-35 (blocks 0..15: t-branch, 16..31: tf) ----------------
__global__ __launch_bounds__(256) void k3_topk(
    const float* __restrict__ amp2part, const float* __restrict__ tfq,
    int* __restrict__ St, int* __restrict__ Stf) {
  int bid = blockIdx.x;
  bool isT = bid < 16;
  int bh = isT ? bid : bid - 16;
  __shared__ float vals[1024];
  __shared__ long long wred[4];
  int tid = threadIdx.x;
  if (isT) {
    for (int l = tid; l < 1024; l += 256) {
      float s = 0.f;
      #pragma unroll
      for (int eg = 0; eg < 16; ++eg)
        s += amp2part[((size_t)bh*16 + eg)*1024 + l];
      vals[l] = s;
    }
  } else {
    int b = bh >> 3, h = bh & 7;
    for (int l = tid; l < 1024; l += 256) {
      const float4* p = reinterpret_cast<const float4*>(
          tfq + (((size_t)(b*1024 + l)*8 + h) << 6));
      float s = 0.f;
      #pragma unroll
      for (int i = 0; i < 16; ++i) {
        float4 v = p[i];
        s += v.x*v.x + v.y*v.y + v.z*v.z + v.w*v.w;
      }
      vals[l] = s;
    }
  }
  __syncthreads();
  int* out = isT ? (St + bh*40) : (Stf + bh*40);
  for (int it = 0; it < NTOP; ++it) {
    long long best = -0x7FFFFFFFFFFFFFFFLL - 1;
    for (int l = tid; l < 1024; l += 256) {
      long long key = ((long long)(int)__float_as_uint(vals[l]) << 32)
                      | (unsigned int)(1023 - l);
      if (key > best) best = key;
    }
    for (int off = 32; off; off >>= 1) {
      long long o = __shfl_down(best, off);
      if (o > best) best = o;
    }
    if ((tid & 63) == 0) wred[tid >> 6] = best;
    __syncthreads();
    if (tid == 0) {
      long long bb = wred[0];
      for (int w = 1; w < 4; ++w) if (wred[w] > bb) bb = wred[w];
      int idx = 1023 - (int)(bb & 0xFFFFFFFFLL);
      out[it] = idx;
      vals[idx] = -1.0f;
    }
    __syncthreads();
  }
}

// ---------------- KW: W[1024][2048] -> Wt[2048][1024], 64x64 LDS tiles ----------------
__global__ __launch_bounds__(256) void kw_trans(
    const float* __restrict__ w, float* __restrict__ Wt) {
  __shared__ float tile[64*65];
  int c0 = blockIdx.x << 6;
  int r0 = blockIdx.y << 6;
  int tid = threadIdx.x;
  #pragma unroll
  for (int s = 0; s < 16; ++s) {
    int idx = tid + (s << 8);
    int r = idx >> 6, c = idx & 63;
    tile[r*65 + c] = w[(size_t)(r0 + r)*2048 + c0 + c];
  }
  __syncthreads();
  #pragma unroll
  for (int s = 0; s < 16; ++s) {
    int idx = tid + (s << 8);
    int c = idx >> 6, r = idx & 63;
    Wt[(size_t)(c0 + c)*1024 + r0 + r] = tile[r*65 + c];
  }
}

// ---------------- KA2: Wg[bh][m][72] from Wt rows via LDS transpose ----------------
__global__ __launch_bounds__(256) void ka2_gather(
    const float* __restrict__ Wt, const float* __restrict__ bias,
    const int* __restrict__ St, const int* __restrict__ Stf,
    float* __restrict__ Wg) {
  int gid = blockIdx.x;                 // 256 = 16 bh x 16 mchunk(64)
  int bh = gid >> 4;  int m0 = (gid & 15) << 6;
  __shared__ int cols[72];
  __shared__ float Wlds[72*65];
  int tid = threadIdx.x;
  if (tid < NTOP)      cols[tid] = St[bh*40 + tid];
  else if (tid < NJ)   cols[tid] = 1024 + Stf[bh*40 + tid - NTOP];
  else if (tid < 72)   cols[tid] = (tid == NJ) ? -1 : -2;
  __syncthreads();
  for (int i = tid; i < 72*64; i += 256) {
    int j = i >> 6, mm = i & 63;
    int c = cols[j];
    float v = (c >= 0) ? Wt[(size_t)c*1024 + m0 + mm]
                       : ((c == -1) ? bias[m0 + mm] : 0.f);
    Wlds[j*65 + mm] = v;
  }
  __syncthreads();
  float* dst = Wg + ((size_t)bh*1024 + m0)*72;
  for (int i = tid; i < 64*72; i += 256) {
    int m = i / 72, j = i - m*72;
    dst[i] = Wlds[j*65 + m];
  }
}

// ---------------- K4: sparse scores + softmax -> P[bh][m][72] ----------------
__global__ __launch_bounds__(256) void k4_scores(
    const float* __restrict__ q, const float* __restrict__ k,
    const float* __restrict__ tfq,
    const int* __restrict__ St, const int* __restrict__ Stf,
    float* __restrict__ P) {
  int gid = blockIdx.x;                 // 256 = 16 bh x 16 mchunk(64)
  int bh = gid >> 4;  int m0 = (gid & 15) << 6;
  int b = bh >> 3, h = bh & 7;
  __shared__ float qs[NTOP*64];
  __shared__ float ts[NTOP*64];
  __shared__ float sc[64*73];
  __shared__ float invs[64];
  int tid = threadIdx.x;
  for (int i = tid; i < NTOP*64; i += 256) {
    int j = i >> 6, e = i & 63;
    int rq = St[bh*40 + j];
    int rt = Stf[bh*40 + j];
    qs[i] = q  [(((size_t)(b*1024 + rq)*8 + h) << 6) + e];
    ts[i] = tfq[(((size_t)(b*1024 + rt)*8 + h) << 6) + e];
  }
  __syncthreads();
  int mi = tid & 63, g = tid >> 6;
  int m = m0 + mi;
  float4 kr[16];
  {
    const float4* p = reinterpret_cast<const float4*>(
        k + (((size_t)(b*1024 + m)*8 + h) << 6));
    #pragma unroll
    for (int i = 0; i < 16; ++i) kr[i] = p[i];
  }
  const float4* qs4 = reinterpret_cast<const float4*>(qs);
  for (int j = g; j < NTOP; j += 4) {
    float s = 0.f;
    #pragma unroll
    for (int e4 = 0; e4 < 16; ++e4) {
      float4 qv = qs4[j*16 + e4];
      s += qv.x*kr[e4].x + qv.y*kr[e4].y + qv.z*kr[e4].z + qv.w*kr[e4].w;
    }
    sc[mi*73 + j] = s * 0.125f;
  }
  {
    const float4* p = reinterpret_cast<const float4*>(
        tfq + (((size_t)(b*1024 + m)*8 + h) << 6));
    #pragma unroll
    for (int i = 0; i < 16; ++i) kr[i] = p[i];
  }
  const float4* ts4 = reinterpret_cast<const float4*>(ts);
  for (int j = g; j < NTOP; j += 4) {
    float s = 0.f;
    #pragma unroll
    for (int e4 = 0; e4 < 16; ++e4) {
      float4 qv = ts4[j*16 + e4];
      s += qv.x*kr[e4].x + qv.y*kr[e4].y + qv.z*kr[e4].z + qv.w*kr[e4].w;
    }
    sc[mi*73 + NTOP + j] = s * 0.125f;
  }
  __syncthreads();
  if (tid < 64) {
    float mx = -1e30f;
    for (int j = 0; j < NJ; ++j) mx = fmaxf(mx, sc[tid*73 + j]);
    float sum = 0.f;
    for (int j = 0; j < NJ; ++j) {
      float e = __expf(sc[tid*73 + j] - mx);
      sc[tid*73 + j] = e; sum += e;
    }
    invs[tid] = 1.0f / sum;
  }
  __syncthreads();
  float* Pb = P + ((size_t)bh*1024 + m0)*72;
  for (int i = tid; i < 64*72; i += 256) {
    int mm = i / 72, j = i - mm*72;
    Pb[i] = (j < NJ) ? sc[mm*73 + j] * invs[mm] : 0.f;
  }
}

// ---------------- KB: partial WV over 256-m chunk ----------------
__global__ __launch_bounds__(256) void kb_wv(
    const float* __restrict__ Wg, const float* __restrict__ values,
    float* __restrict__ WVp) {
  int jq = blockIdx.x;                  // 0..17 -> j0 = 4*jq
  int bh = blockIdx.y;                  // 0..15
  int mc = blockIdx.z;                  // 0..3  -> m in [256*mc, 256*mc+256)
  int b = bh >> 3, h = bh & 7;
  int j0 = jq << 2;
  int tid = threadIdx.x;
  int d = tid & 63, mp = tid >> 6;
  int m0 = (mc << 8) + mp;
  float a0=0.f, a1=0.f, a2=0.f, a3=0.f;
  const float* Wgb = Wg + (size_t)bh*1024*72;
  #pragma unroll 16
  for (int i = 0; i < 64; ++i) {
    int m = m0 + (i << 2);
    float vv = values[(((size_t)(b*1024 + m)*8 + h) << 6) + d];
    float4 wv = *reinterpret_cast<const float4*>(Wgb + (size_t)m*72 + j0);
    a0 = fmaf(wv.x, vv, a0); a1 = fmaf(wv.y, vv, a1);
    a2 = fmaf(wv.z, vv, a2); a3 = fmaf(wv.w, vv, a3);
  }
  __shared__ float4 red[256];
  red[tid] = make_float4(a0, a1, a2, a3);
  __syncthreads();
  int jj = tid >> 6, dd = tid & 63;
  float4 r0 = red[dd], r1 = red[64+dd], r2 = red[128+dd], r3 = red[192+dd];
  float s;
  if (jj == 0)      s = r0.x + r1.x + r2.x + r3.x;
  else if (jj == 1) s = r0.y + r1.y + r2.y + r3.y;
  else if (jj == 2) s = r0.z + r1.z + r2.z + r3.z;
  else              s = r0.w + r1.w + r2.w + r3.w;
  WVp[(size_t)mc*73728 + ((size_t)bh*72 + j0 + jj)*64 + dd] = s;
}

// ---------------- KC: WV = sum_mc WVp ----------------
__global__ __launch_bounds__(256) void kc_comb(
    const float* __restrict__ WVp, float* __restrict__ WV) {
  int idx = blockIdx.x*256 + threadIdx.x;   // < 73728
  WV[idx] = WVp[idx] + WVp[73728 + idx] + WVp[147456 + idx] + WVp[221184 + idx];
}

// ---------------- K6: out[b,l,h,d] ----------------
__global__ __launch_bounds__(512) void k6_out(
    const float* __restrict__ P, const float* __restrict__ WV,
    float* __restrict__ out) {
  int l = blockIdx.x, b = blockIdx.y;
  int tid = threadIdx.x;
  int h = tid >> 6, d = tid & 63;
  int bh = b*8 + h;
  const float* Pr = P + ((size_t)bh*1024 + l)*72;
  const float* Wv = WV + (size_t)bh*72*64;
  float acc = Wv[NJ*64 + d];
  for (int j = 0; j < NJ; ++j) acc = fmaf(Pr[j], Wv[j*64 + d], acc);
  out[(((size_t)(b*1024 + l)*8 + h) << 6) + d] = acc;
}

extern "C" void kernel_launch(void* const* d_in, const int* in_sizes, int n_in,
                              void* d_out, int out_size, void* d_ws, size_t ws_size,
                              hipStream_t stream) {
  const float* tfq  = (const float*)d_in[0];
  const float* q    = (const float*)d_in[1];
  const float* k    = (const float*)d_in[2];
  const float* v    = (const float*)d_in[3];
  const float* tw   = (const float*)d_in[5];
  const float* tb   = (const float*)d_in[6];
  float* out = (float*)d_out;

  char* ws = (char*)d_ws;
  float* acp      = (float*)(ws);                   // 16,777,216
  float* amp2part = (float*)(ws + 16777216);        // 1,048,576
  int*   St       = (int*)  (ws + 17825792);        // 4 KB
  int*   Stf      = (int*)  (ws + 17829888);        // 4 KB
  float* Qc       = (float*)(ws + 17833984);        // 4,194,304
  float* Kc       = (float*)(ws + 22028288);        // 4,194,304
  float* Wt       = (float*)(ws + 26222592);        // 8,388,608
  float* Wg       = (float*)(ws + 34611200);        // 4,718,592
  float* P        = (float*)(ws + 39329792);        // 4,718,592
  float* WV       = (float*)(ws + 44048384);        // 294,912
  float* WVp      = (float*)(ws + 44343296);        // 1,179,648

  k0_trans  <<<256, 256, 0, stream>>>(q, k, Qc, Kc);
  k1_corr   <<<1024, 256, 0, stream>>>(Qc, Kc, acp);
  k2_combine<<<256, 256, 0, stream>>>(acp, amp2part);
  k3_topk   <<<32, 256, 0, stream>>>(amp2part, tfq, St, Stf);
  kw_trans  <<<dim3(32, 16), 256, 0, stream>>>(tw, Wt);
  ka2_gather<<<256, 256, 0, stream>>>(Wt, tb, St, Stf, Wg);
  k4_scores <<<256, 256, 0, stream>>>(q, k, tfq, St, Stf, P);
  kb_wv     <<<dim3(18, 16, 4), 256, 0, stream>>>(Wg, v, WVp);
  kc_comb   <<<288, 256, 0, stream>>>(WVp, WV);
  k6_out    <<<dim3(1024, 2), 512, 0, stream>>>(P, WV, out);
}